// Round 1
// baseline (2257.302 us; speedup 1.0000x reference)
//
#include <hip/hip_runtime.h>
#include <stdint.h>

#define DI __device__ __forceinline__

typedef _Float16 f16x8 __attribute__((ext_vector_type(8)));
typedef float f32x4 __attribute__((ext_vector_type(4)));

// ---- problem constants ----
constexpr int kB = 4;
constexpr int kN = 65536;
constexpr int kG = 512;   // NUM_GROUP
constexpr int kM = 64;    // GROUP_SIZE
constexpr int kE = 60;    // EMB
constexpr int GRD = 20;   // KNN grid resolution
constexpr int NCELL = GRD * GRD * GRD;
constexpr float CW = 1.0f / 20.0f;

constexpr int FPS_SUB = 16;                   // blocks per batch
constexpr int FPS_PT_T = kN / FPS_SUB / 1024; // points per thread = 4

// ---- workspace layout (bytes) ----
// fkey: per-iteration publication slots: [b][it][sub][4] u64
//   word0 = (dist_bits<<32)|(0xFFFFFFFF-p)   (always nonzero once written)
//   word1 = (x_bits<<32)|it, word2 = (y_bits<<32)|it, word3 = (z_bits<<32)|it
constexpr size_t OFF_FKEY   = 0;
constexpr size_t OFF_CCNT   = OFF_FKEY + (size_t)kB * kG * FPS_SUB * 4 * 8; // cell counts
constexpr size_t ZERO_BYTES = OFF_CCNT + (size_t)kB * NCELL * 4;
constexpr size_t OFF_CSTART = (ZERO_BYTES + 255) & ~(size_t)255;            // kB*(NCELL+1) u32
constexpr size_t OFF_CUR    = OFF_CSTART + (size_t)kB * (NCELL + 1) * 4;    // scatter cursors
// swizzled f16 weights (B-fragment order) + f32 transposed Wp
constexpr size_t OFF_SW1    = ((OFF_CUR + (size_t)kB * NCELL * 4) + 255) & ~(size_t)255;
constexpr size_t OFF_SW2    = OFF_SW1 + 2048 * 2;    // L1: 4nt*1ks*512
constexpr size_t OFF_SW3    = OFF_SW2 + 8192 * 2;    // L2: 8nt*2ks*512
constexpr size_t OFF_SW4    = OFF_SW3 + 32768 * 2;   // L3: 16nt*4ks*512
constexpr size_t OFF_WPT    = OFF_SW4 + 131072 * 2;  // L4: 32nt*8ks*512
constexpr size_t OFF_SORT   = ((OFF_WPT + 60 * 512 * 4) + 255) & ~(size_t)255; // kB*kN float4
constexpr size_t OFF_KIDX   = OFF_SORT + (size_t)kB * kN * 16; // kB*kG*kM u32

DI int cellof(float x) {
  int c = (int)(x * (float)GRD);
  return min(GRD - 1, max(0, c));
}
DI unsigned orderable(float f) {
  unsigned u = __float_as_uint(f);
  return (u & 0x80000000u) ? ~u : (u | 0x80000000u);
}

// =====================  zero the sync/count region  =====================
__global__ void k_zero(uint32_t* p, int nwords) {
  int i = blockIdx.x * blockDim.x + threadIdx.x;
  int st = gridDim.x * blockDim.x;
  for (; i < nwords; i += st) p[i] = 0u;
}

// =====================  weight prep: B-fragment swizzle (f16) + WpT  =====================
// sw layout per layer: [(nt*nks + ks)*64 + lane]*8 + j  ->  W[k][n], k=ks*32+(lane>>4)*8+j,
// n=nt*16+(lane&15). Zero-pad k >= Kreal.
DI void swz(const float* __restrict__ W, _Float16* __restrict__ sw,
            int total, int nks, int Kreal, int N, int i0, int st) {
  for (int i = i0; i < total; i += st) {
    int j = i & 7, lane = (i >> 3) & 63, rest = i >> 9;
    int ks = rest % nks, nt = rest / nks;
    int k = ks * 32 + ((lane >> 4) << 3) + j;
    int n = nt * 16 + (lane & 15);
    sw[i] = (_Float16)((k < Kreal) ? W[k * N + n] : 0.f);
  }
}

__global__ void k_prep(const float* __restrict__ W1, const float* __restrict__ W2,
                       const float* __restrict__ W3, const float* __restrict__ W4,
                       const float* __restrict__ Wp,
                       _Float16* __restrict__ sw1, _Float16* __restrict__ sw2,
                       _Float16* __restrict__ sw3, _Float16* __restrict__ sw4,
                       float* __restrict__ wpt) {
  int i0 = blockIdx.x * blockDim.x + threadIdx.x;
  int st = gridDim.x * blockDim.x;
  swz(W1, sw1, 2048, 1, 6, 64, i0, st);
  swz(W2, sw2, 8192, 2, 64, 128, i0, st);
  swz(W3, sw3, 32768, 4, 128, 256, i0, st);
  swz(W4, sw4, 131072, 8, 256, 512, i0, st);
  for (int i = i0; i < 60 * 512; i += st) { int n = i >> 9, k = i & 511; wpt[i] = Wp[k * 60 + n]; }
}

// =====================  FPS  =====================
// Sync scheme: per iteration, each block's leader publishes {key, x, y, z} as four
// self-validating relaxed u64 words. One leader wave polls all 64 words (16 blocks x 4);
// once all are valid the winner AND its coords are already in lane registers (via shfl).
// No release/acquire chain, no counter, no dependent coord gather.
__global__ __launch_bounds__(1024) void k_fps(const float* __restrict__ xyz,
                                              float* __restrict__ outC,
                                              unsigned long long* __restrict__ fkey) {
  const int b = blockIdx.x / FPS_SUB, sub = blockIdx.x % FPS_SUB;
  const int tid = threadIdx.x;
  const int wave = tid >> 6, lane = tid & 63;
  const float* X = xyz + (size_t)b * kN * 3;
  float px[FPS_PT_T], py[FPS_PT_T], pz[FPS_PT_T], dd[FPS_PT_T];
#pragma unroll
  for (int j = 0; j < FPS_PT_T; ++j) {
    int p = sub * (kN / FPS_SUB) + j * 1024 + tid;
    px[j] = X[3 * p]; py[j] = X[3 * p + 1]; pz[j] = X[3 * p + 2];
    dd[j] = 1e10f;
  }
  float lx = X[0], ly = X[1], lz = X[2];
  if (sub == 0 && tid == 0) {
    outC[(size_t)b * kG * 3 + 0] = lx;
    outC[(size_t)b * kG * 3 + 1] = ly;
    outC[(size_t)b * kG * 3 + 2] = lz;
  }
  __shared__ unsigned long long wkey[16];
  __shared__ float wx[16], wy[16], wz[16];
  __shared__ float4 sp;
  unsigned long long* keyB = fkey + (size_t)b * kG * FPS_SUB * 4;

  for (int it = 1; it < kG; ++it) {
    unsigned long long best = 0ull;
    float bx = 0.f, by = 0.f, bz = 0.f;
#pragma unroll
    for (int j = 0; j < FPS_PT_T; ++j) {
      float dx = __fsub_rn(px[j], lx);
      float dy = __fsub_rn(py[j], ly);
      float dz = __fsub_rn(pz[j], lz);
      float d = __fadd_rn(__fadd_rn(__fmul_rn(dx, dx), __fmul_rn(dy, dy)), __fmul_rn(dz, dz));
      float nd = fminf(dd[j], d);
      dd[j] = nd;
      int p = sub * (kN / FPS_SUB) + j * 1024 + tid;
      unsigned long long pk =
          ((unsigned long long)__float_as_uint(nd) << 32) | (unsigned)(0xFFFFFFFFu - (unsigned)p);
      if (pk > best) { best = pk; bx = px[j]; by = py[j]; bz = pz[j]; }
    }
    // wave reduce, carrying coords (keeps winner coords in registers; no gather later)
#pragma unroll
    for (int off = 32; off; off >>= 1) {
      unsigned long long ok = __shfl_down(best, (unsigned)off);
      float ox = __shfl_down(bx, (unsigned)off);
      float oy = __shfl_down(by, (unsigned)off);
      float oz = __shfl_down(bz, (unsigned)off);
      if (ok > best) { best = ok; bx = ox; by = oy; bz = oz; }
    }
    if (lane == 0) { wkey[wave] = best; wx[wave] = bx; wy[wave] = by; wz[wave] = bz; }
    __syncthreads();
    if (wave == 0) {
      // cross-wave reduce on lanes 0..15 (redundant on upper lanes, harmless)
      int i16 = lane & 15;
      unsigned long long kk = wkey[i16];
      float kx = wx[i16], ky = wy[i16], kz = wz[i16];
#pragma unroll
      for (int off = 8; off; off >>= 1) {
        unsigned long long ok = __shfl_down(kk, (unsigned)off);
        float ox = __shfl_down(kx, (unsigned)off);
        float oy = __shfl_down(ky, (unsigned)off);
        float oz = __shfl_down(kz, (unsigned)off);
        if (ok > kk) { kk = ok; kx = ox; ky = oy; kz = oz; }
      }
      unsigned long long* slots = keyB + (size_t)it * (FPS_SUB * 4);
      if (lane == 0) {
        unsigned long long tag = (unsigned)it;
        unsigned long long* my = slots + sub * 4;
        __hip_atomic_store(my + 1, ((unsigned long long)__float_as_uint(kx) << 32) | tag,
                           __ATOMIC_RELAXED, __HIP_MEMORY_SCOPE_AGENT);
        __hip_atomic_store(my + 2, ((unsigned long long)__float_as_uint(ky) << 32) | tag,
                           __ATOMIC_RELAXED, __HIP_MEMORY_SCOPE_AGENT);
        __hip_atomic_store(my + 3, ((unsigned long long)__float_as_uint(kz) << 32) | tag,
                           __ATOMIC_RELAXED, __HIP_MEMORY_SCOPE_AGENT);
        __hip_atomic_store(my + 0, kk, __ATOMIC_RELAXED, __HIP_MEMORY_SCOPE_AGENT);
      }
      // poll: lane L watches word L of the 16x4 slot block
      unsigned long long v;
      bool ok;
      long bail = 0;
      do {
        v = __hip_atomic_load(slots + lane, __ATOMIC_RELAXED, __HIP_MEMORY_SCOPE_AGENT);
        ok = (lane & 3) ? ((unsigned)v == (unsigned)it) : (v != 0ull);
      } while (!__all(ok) && ++bail < 100000000L);
      // winner reduce over the 16 key lanes
      unsigned long long key = (lane & 3) ? 0ull : v;
      int slot = lane >> 2;
#pragma unroll
      for (int off = 32; off; off >>= 1) {
        unsigned long long ok2 = __shfl_down(key, (unsigned)off);
        int os = __shfl_down(slot, (unsigned)off);
        if (ok2 > key) { key = ok2; slot = os; }
      }
      slot = __shfl(slot, 0);
      unsigned long long vx = __shfl(v, slot * 4 + 1);
      unsigned long long vy = __shfl(v, slot * 4 + 2);
      unsigned long long vz = __shfl(v, slot * 4 + 3);
      if (lane == 0) {
        float wxc = __uint_as_float((unsigned)(vx >> 32));
        float wyc = __uint_as_float((unsigned)(vy >> 32));
        float wzc = __uint_as_float((unsigned)(vz >> 32));
        sp = make_float4(wxc, wyc, wzc, 0.f);
        if (sub == 0) {
          outC[((size_t)b * kG + it) * 3 + 0] = wxc;
          outC[((size_t)b * kG + it) * 3 + 1] = wyc;
          outC[((size_t)b * kG + it) * 3 + 2] = wzc;
        }
      }
    }
    __syncthreads();
    lx = sp.x; ly = sp.y; lz = sp.z;
  }
}

// =====================  grid build  =====================
__global__ void k_cellcount(const float* __restrict__ xyz, uint32_t* __restrict__ ccnt) {
  int i = blockIdx.x * blockDim.x + threadIdx.x;
  int st = gridDim.x * blockDim.x;
  for (; i < kB * kN; i += st) {
    int b = i >> 16, p = i & (kN - 1);
    const float* q = xyz + ((size_t)b * kN + p) * 3;
    int cid = (cellof(q[2]) * GRD + cellof(q[1])) * GRD + cellof(q[0]);
    atomicAdd(&ccnt[b * NCELL + cid], 1u);
  }
}

__global__ void k_scan(const uint32_t* __restrict__ ccnt, uint32_t* __restrict__ cstart,
                       uint32_t* __restrict__ cur) {
  int b = blockIdx.x, tid = threadIdx.x;
  const uint32_t* cc = ccnt + (size_t)b * NCELL;
  uint32_t* cs = cstart + (size_t)b * (NCELL + 1);
  uint32_t* cu = cur + (size_t)b * NCELL;
  __shared__ uint32_t part[256];
  const int chunk = 32;
  int c0 = tid * chunk;
  uint32_t s = 0;
  for (int i = 0; i < chunk; ++i) { int c = c0 + i; if (c < NCELL) s += cc[c]; }
  part[tid] = s;
  __syncthreads();
  for (int off = 1; off < 256; off <<= 1) {
    uint32_t add = (tid >= off) ? part[tid - off] : 0u;
    __syncthreads();
    part[tid] += add;
    __syncthreads();
  }
  uint32_t run = part[tid] - s;  // exclusive prefix
  for (int i = 0; i < chunk; ++i) {
    int c = c0 + i;
    if (c < NCELL) { cs[c] = run; cu[c] = run; run += cc[c]; }
  }
  if (tid == 255) cs[NCELL] = run;
}

__global__ void k_scatter(const float* __restrict__ xyz, uint32_t* __restrict__ cur,
                          float4* __restrict__ sorted) {
  int i = blockIdx.x * blockDim.x + threadIdx.x;
  int st = gridDim.x * blockDim.x;
  for (; i < kB * kN; i += st) {
    int b = i >> 16, p = i & (kN - 1);
    const float* q = xyz + ((size_t)b * kN + p) * 3;
    float x = q[0], y = q[1], z = q[2];
    int cid = (cellof(z) * GRD + cellof(y)) * GRD + cellof(x);
    uint32_t pos = atomicAdd(&cur[b * NCELL + cid], 1u);
    sorted[(size_t)b * kN + pos] = make_float4(x, y, z, __uint_as_float((unsigned)p));
  }
}

// =====================  KNN (expanding box + exact re-rank + bitonic)  =====================
constexpr int CAP = 8192;

DI void bitonic(unsigned long long* a, int n, int tid) {
  for (int k = 2; k <= n; k <<= 1)
    for (int j = k >> 1; j > 0; j >>= 1) {
      __syncthreads();
      for (int i = tid; i < n; i += 256) {
        int ix = i ^ j;
        if (ix > i) {
          unsigned long long x = a[i], y = a[ix];
          bool up = ((i & k) == 0);
          if ((x > y) == up) { a[i] = y; a[ix] = x; }
        }
      }
    }
  __syncthreads();
}

__global__ __launch_bounds__(256) void k_knn(const float4* __restrict__ sorted,
                                             const uint32_t* __restrict__ cstart,
                                             const float* __restrict__ outC,
                                             uint32_t* __restrict__ kidx) {
  const int bi = blockIdx.x;
  const int b = (bi & 7) >> 1;
  const int g = ((bi >> 3) << 1) | (bi & 1);
  const int tid = threadIdx.x;
  __shared__ unsigned long long cand[CAP];
  __shared__ int nC;
  const float cx = outC[((size_t)b * kG + g) * 3 + 0];
  const float cy = outC[((size_t)b * kG + g) * 3 + 1];
  const float cz = outC[((size_t)b * kG + g) * 3 + 2];
  const float nc = __fadd_rn(__fadd_rn(__fmul_rn(cx, cx), __fmul_rn(cy, cy)), __fmul_rn(cz, cz));
  const float4* SP = sorted + (size_t)b * kN;
  const uint32_t* CS = cstart + (size_t)b * (NCELL + 1);
  const int ccx = cellof(cx), ccy = cellof(cy), ccz = cellof(cz);
  if (tid == 0) nC = 0;
  __syncthreads();
  int plox = 1, phix = 0, ploy = 1, phiy = 0, ploz = 1, phiz = 0;
  for (int r = 1; r <= GRD; ++r) {
    int lox = max(0, ccx - r), hix = min(GRD - 1, ccx + r);
    int loy = max(0, ccy - r), hiy = min(GRD - 1, ccy + r);
    int loz = max(0, ccz - r), hiz = min(GRD - 1, ccz + r);
    for (int z = loz; z <= hiz; ++z)
      for (int y = loy; y <= hiy; ++y) {
        bool rowPrev = (r > 1) && (z >= ploz && z <= phiz && y >= ploy && y <= phiy);
        for (int s = 0; s < 2; ++s) {
          int xa, xb;
          if (!rowPrev) { if (s) break; xa = lox; xb = hix; }
          else if (s == 0) { xa = lox; xb = plox - 1; }
          else { xa = phix + 1; xb = hix; }
          if (xa > xb) continue;
          int c0 = (z * GRD + y) * GRD + xa;
          int i0 = CS[c0];
          int i1 = CS[(z * GRD + y) * GRD + xb + 1];
          for (int i = i0 + tid; i < i1; i += 256) {
            float4 pt = SP[i];
            float npn = __fadd_rn(__fadd_rn(__fmul_rn(pt.x, pt.x), __fmul_rn(pt.y, pt.y)),
                                  __fmul_rn(pt.z, pt.z));
            float dot = __fadd_rn(__fadd_rn(__fmul_rn(cx, pt.x), __fmul_rn(cy, pt.y)),
                                  __fmul_rn(cz, pt.z));
            float sq = __fsub_rn(__fadd_rn(nc, npn), __fmul_rn(2.0f, dot));
            unsigned key = orderable(sq);
            int pos = atomicAdd(&nC, 1);
            if (pos < CAP)
              cand[pos] = ((unsigned long long)key << 32) | (unsigned)__float_as_uint(pt.w);
          }
        }
      }
    __syncthreads();
    int n = min(nC, CAP);
    float rc = 1e30f;
    if (lox > 0) rc = fminf(rc, cx - (float)lox * CW);
    if (hix < GRD - 1) rc = fminf(rc, (float)(hix + 1) * CW - cx);
    if (loy > 0) rc = fminf(rc, cy - (float)loy * CW);
    if (hiy < GRD - 1) rc = fminf(rc, (float)(hiy + 1) * CW - cy);
    if (loz > 0) rc = fminf(rc, cz - (float)loz * CW);
    if (hiz < GRD - 1) rc = fminf(rc, (float)(hiz + 1) * CW - cz);
    float r2 = (rc >= 1e29f) ? 3.0e38f : rc * rc * (1.0f - 1e-5f);
    unsigned keyR = orderable(r2);
    bool done = false;
    if (n >= kM) {
      int np2 = 1;
      while (np2 < n) np2 <<= 1;
      for (int i = n + tid; i < np2; i += 256) cand[i] = ~0ull;
      bitonic(cand, np2, tid);
      unsigned k63 = (unsigned)(cand[kM - 1] >> 32);
      done = (k63 <= keyR);
      if (tid == 0) nC = n;
    }
    __syncthreads();
    if (done) break;
    plox = lox; phix = hix; ploy = loy; phiy = hiy; ploz = loz; phiz = hiz;
  }
  if (tid < kM)
    kidx[((size_t)b * kG + g) * kM + tid] = (uint32_t)(cand[tid] & 0xFFFFFFFFu);
}

// =====================  fused per-group MLP — f16 MFMA  =====================
// One block = one group. 4 waves; wave w owns cols [w*N/4, (w+1)*N/4).
// A-frag: lane holds X[m16 + (lane&15)][ks*32 + (lane>>4)*8 + j]  (ds_read_b128)
// B-frag: lane holds W[ks*32 + (lane>>4)*8 + j][n0 + (lane&15)]   (pre-swizzled, 16B global)
// D: lane reg r = D[(lane>>4)*4 + r][lane&15]

template <int Kdim, int Ndim, int SIN, int SOUT>
DI void mfma_layer(const _Float16* __restrict__ Xin, _Float16* __restrict__ Xout,
                   const _Float16* __restrict__ Wsw, const float* __restrict__ bias,
                   int wave, int lane) {
  constexpr int NKS = Kdim / 32;
  constexpr int NTW = Ndim / 64;               // n-tiles per wave
  constexpr int CH = (NTW < 4) ? NTW : 4;      // acc chunk
  const int quad = lane >> 4, l16 = lane & 15;
  for (int c0 = 0; c0 < NTW; c0 += CH) {
    f32x4 acc[CH][4];
#pragma unroll
    for (int nt = 0; nt < CH; ++nt) {
      float bv = bias[wave * (Ndim / 4) + (c0 + nt) * 16 + l16];
#pragma unroll
      for (int m = 0; m < 4; ++m) acc[nt][m] = {bv, bv, bv, bv};
    }
#pragma unroll
    for (int ks = 0; ks < NKS; ++ks) {
      f16x8 af[4];
#pragma unroll
      for (int m = 0; m < 4; ++m)
        af[m] = *(const f16x8*)(Xin + (m * 16 + l16) * SIN + ks * 32 + quad * 8);
#pragma unroll
      for (int nt = 0; nt < CH; ++nt) {
        int ntg = wave * NTW + c0 + nt;
        f16x8 bf = *(const f16x8*)(Wsw + ((size_t)(ntg * NKS + ks) * 64 + lane) * 8);
#pragma unroll
        for (int m = 0; m < 4; ++m)
          acc[nt][m] = __builtin_amdgcn_mfma_f32_16x16x32_f16(af[m], bf, acc[nt][m], 0, 0, 0);
      }
    }
#pragma unroll
    for (int nt = 0; nt < CH; ++nt) {
      int col = wave * (Ndim / 4) + (c0 + nt) * 16 + l16;
#pragma unroll
      for (int m = 0; m < 4; ++m)
#pragma unroll
        for (int r = 0; r < 4; ++r) {
          int row = m * 16 + quad * 4 + r;
          Xout[row * SOUT + col] = (_Float16)fmaxf(acc[nt][m][r], 0.f);
        }
    }
  }
}

DI void mfma_layer4(const _Float16* __restrict__ Xin, const _Float16* __restrict__ Wsw,
                    const float* __restrict__ bias, float* __restrict__ maxv,
                    int wave, int lane) {
  constexpr int SIN = 264, NKS = 8, NTW = 8, CH = 4;
  const int quad = lane >> 4, l16 = lane & 15;
  for (int c0 = 0; c0 < NTW; c0 += CH) {
    f32x4 acc[CH][4];
#pragma unroll
    for (int nt = 0; nt < CH; ++nt) {
      float bv = bias[wave * 128 + (c0 + nt) * 16 + l16];
#pragma unroll
      for (int m = 0; m < 4; ++m) acc[nt][m] = {bv, bv, bv, bv};
    }
#pragma unroll
    for (int ks = 0; ks < NKS; ++ks) {
      f16x8 af[4];
#pragma unroll
      for (int m = 0; m < 4; ++m)
        af[m] = *(const f16x8*)(Xin + (m * 16 + l16) * SIN + ks * 32 + quad * 8);
#pragma unroll
      for (int nt = 0; nt < CH; ++nt) {
        int ntg = wave * NTW + c0 + nt;
        f16x8 bf = *(const f16x8*)(Wsw + ((size_t)(ntg * NKS + ks) * 64 + lane) * 8);
#pragma unroll
        for (int m = 0; m < 4; ++m)
          acc[nt][m] = __builtin_amdgcn_mfma_f32_16x16x32_f16(af[m], bf, acc[nt][m], 0, 0, 0);
      }
    }
#pragma unroll
    for (int nt = 0; nt < CH; ++nt) {
      float mx = 0.f;  // relu folded into max
#pragma unroll
      for (int m = 0; m < 4; ++m)
#pragma unroll
        for (int r = 0; r < 4; ++r) mx = fmaxf(mx, acc[nt][m][r]);
      mx = fmaxf(mx, __shfl_xor(mx, 16, 64));
      mx = fmaxf(mx, __shfl_xor(mx, 32, 64));
      if (quad == 0) maxv[wave * 128 + (c0 + nt) * 16 + l16] = mx;
    }
  }
}

__global__ __launch_bounds__(256) void k_mlp(
    const float* __restrict__ xyz, const float* __restrict__ color,
    const float* __restrict__ outC, const uint32_t* __restrict__ kidx,
    const _Float16* __restrict__ sw1, const _Float16* __restrict__ sw2,
    const _Float16* __restrict__ sw3, const _Float16* __restrict__ sw4,
    const float* __restrict__ wpt,
    const float* __restrict__ b1, const float* __restrict__ b2,
    const float* __restrict__ b3, const float* __restrict__ b4,
    const float* __restrict__ bp, float* __restrict__ outE) {
  const int bi = blockIdx.x;
  const int b = (bi & 7) >> 1;
  const int g = ((bi >> 3) << 1) | (bi & 1);
  const int tid = threadIdx.x;
  const int wave = tid >> 6, lane = tid & 63;
  // bufA: X0 (stride 40, 5120B) then X2 (stride 136, 17408B)
  // bufB: X1 (stride 72, 9216B) then X3 (stride 264, 33792B)
  // maxv/psum alias bufA (X0/X2 dead by the time they're written)
  __shared__ __align__(16) char smem[17408 + 33792];
  _Float16* bufA = (_Float16*)smem;
  _Float16* bufB = (_Float16*)(smem + 17408);
  float* maxv = (float*)smem;              // 512 f32 = 2048 B
  float* psum = (float*)(smem + 2048);     // 240 f32

  if (tid < kM) {
    uint32_t p = kidx[((size_t)b * kG + g) * kM + tid];
    const float* cen = outC + ((size_t)b * kG + g) * 3;
    const float* xp = xyz + ((size_t)b * kN + p) * 3;
    const float* cp = color + ((size_t)b * kN + p) * 3;
    f16x8 v = {};
    v[0] = (_Float16)__fsub_rn(xp[0], cen[0]);
    v[1] = (_Float16)__fsub_rn(xp[1], cen[1]);
    v[2] = (_Float16)__fsub_rn(xp[2], cen[2]);
    v[3] = (_Float16)cp[0];
    v[4] = (_Float16)cp[1];
    v[5] = (_Float16)cp[2];
    f16x8 z = {};
    *(f16x8*)(bufA + tid * 40 + 0) = v;
    *(f16x8*)(bufA + tid * 40 + 8) = z;
    *(f16x8*)(bufA + tid * 40 + 16) = z;
    *(f16x8*)(bufA + tid * 40 + 24) = z;
  }
  __syncthreads();
  mfma_layer<32, 64, 40, 72>(bufA, bufB, sw1, b1, wave, lane);    // X0 -> X1
  __syncthreads();
  mfma_layer<64, 128, 72, 136>(bufB, bufA, sw2, b2, wave, lane);  // X1 -> X2
  __syncthreads();
  mfma_layer<128, 256, 136, 264>(bufA, bufB, sw3, b3, wave, lane);// X2 -> X3
  __syncthreads();
  mfma_layer4(bufB, sw4, b4, maxv, wave, lane);                   // X3 -> maxv (aliases bufA)
  __syncthreads();
  if (tid < 240) {
    int j = tid >> 2, q = tid & 3;
    const float* w = wpt + (size_t)j * 512 + q * 128;
    float s = 0.f;
#pragma unroll 4
    for (int k = 0; k < 128; ++k) s = fmaf(maxv[q * 128 + k], w[k], s);
    psum[tid] = s;
  }
  __syncthreads();
  if (tid < kE) {
    float e = __fadd_rn(__fadd_rn(psum[tid * 4 + 0], psum[tid * 4 + 1]),
                        __fadd_rn(psum[tid * 4 + 2], psum[tid * 4 + 3])) + bp[tid];
    outE[((size_t)b * kG + g) * kE + tid] = e;
  }
}

// =====================  launch  =====================
extern "C" void kernel_launch(void* const* d_in, const int* in_sizes, int n_in,
                              void* d_out, int out_size, void* d_ws, size_t ws_size,
                              hipStream_t stream) {
  (void)in_sizes; (void)n_in; (void)out_size; (void)ws_size;
  const float* xyz = (const float*)d_in[0];
  const float* color = (const float*)d_in[1];
  const float* W1 = (const float*)d_in[2];
  const float* b1 = (const float*)d_in[3];
  const float* W2 = (const float*)d_in[4];
  const float* b2 = (const float*)d_in[5];
  const float* W3 = (const float*)d_in[6];
  const float* b3 = (const float*)d_in[7];
  const float* W4 = (const float*)d_in[8];
  const float* b4 = (const float*)d_in[9];
  const float* Wp = (const float*)d_in[10];
  const float* bp = (const float*)d_in[11];

  char* ws = (char*)d_ws;
  auto fkey = (unsigned long long*)(ws + OFF_FKEY);
  auto ccnt = (uint32_t*)(ws + OFF_CCNT);
  auto cstart = (uint32_t*)(ws + OFF_CSTART);
  auto cur = (uint32_t*)(ws + OFF_CUR);
  auto sw1 = (_Float16*)(ws + OFF_SW1);
  auto sw2 = (_Float16*)(ws + OFF_SW2);
  auto sw3 = (_Float16*)(ws + OFF_SW3);
  auto sw4 = (_Float16*)(ws + OFF_SW4);
  auto wpt = (float*)(ws + OFF_WPT);
  auto sorted = (float4*)(ws + OFF_SORT);
  auto kidx = (uint32_t*)(ws + OFF_KIDX);

  float* outE = (float*)d_out;
  float* outC = outE + (size_t)kB * kG * kE;

  k_zero<<<128, 256, 0, stream>>>((uint32_t*)ws, (int)(ZERO_BYTES / 4));
  k_prep<<<256, 256, 0, stream>>>(W1, W2, W3, W4, Wp, sw1, sw2, sw3, sw4, wpt);
  k_fps<<<kB * FPS_SUB, 1024, 0, stream>>>(xyz, outC, fkey);
  k_cellcount<<<512, 256, 0, stream>>>(xyz, ccnt);
  k_scan<<<kB, 256, 0, stream>>>(ccnt, cstart, cur);
  k_scatter<<<512, 256, 0, stream>>>(xyz, cur, sorted);
  k_knn<<<kB * kG, 256, 0, stream>>>(sorted, cstart, outC, kidx);
  k_mlp<<<kB * kG, 256, 0, stream>>>(xyz, color, outC, kidx, sw1, sw2, sw3, sw4, wpt,
                                     b1, b2, b3, b4, bp, outE);
}

// Round 2
// 2128.327 us; speedup vs baseline: 1.0606x; 1.0606x over previous
//
#include <hip/hip_runtime.h>
#include <stdint.h>

#define DI __device__ __forceinline__

typedef _Float16 f16x8 __attribute__((ext_vector_type(8)));
typedef float f32x4 __attribute__((ext_vector_type(4)));
typedef unsigned long long u64;

// ---- problem constants ----
constexpr int kB = 4;
constexpr int kN = 65536;
constexpr int kG = 512;   // NUM_GROUP
constexpr int kM = 64;    // GROUP_SIZE
constexpr int kE = 60;    // EMB
constexpr int GRD = 20;   // KNN grid resolution
constexpr int NCELL = GRD * GRD * GRD;
constexpr float CW = 1.0f / 20.0f;

constexpr int FPS_SUB = 8;                      // fps blocks per batch
constexpr int FPS_TPB = 256;                    // fps threads per block
constexpr int FPS_PT_T = kN / FPS_SUB / FPS_TPB; // 32 points per thread
constexpr int NFPS = kB * FPS_SUB;              // 32 fps blocks
constexpr int NWORK = 448;                      // worker blocks (grid build + knn + mlp)
constexpr int NBLK = NFPS + NWORK;              // 480 blocks, all co-resident (2/CU @66KB LDS)

// ---- workspace layout (bytes) ----
// fkey slots per (b,it): FPS_SUB*4 u64, self-validating:
//   word0 = (dist_bits<<32)|(0xFFFFFFFF-p)  (nonzero once written)
//   word1..3 = (x/y/z bits<<32)|it
constexpr size_t OFF_FKEY   = 0;
constexpr size_t OFF_CCNT   = OFF_FKEY + (size_t)kB * kG * FPS_SUB * 4 * 8;
constexpr size_t OFF_GS     = OFF_CCNT + (size_t)kB * NCELL * 4;   // 16 u32 phase counters
constexpr size_t ZERO_BYTES = OFF_GS + 64;
constexpr size_t OFF_CSTART = (ZERO_BYTES + 255) & ~(size_t)255;   // kB*(NCELL+1) u32
constexpr size_t OFF_CUR    = OFF_CSTART + (size_t)kB * (NCELL + 1) * 4;
constexpr size_t OFF_SW1    = ((OFF_CUR + (size_t)kB * NCELL * 4) + 255) & ~(size_t)255;
constexpr size_t OFF_SW2    = OFF_SW1 + 2048 * 2;
constexpr size_t OFF_SW3    = OFF_SW2 + 8192 * 2;
constexpr size_t OFF_SW4    = OFF_SW3 + 32768 * 2;
constexpr size_t OFF_WPT    = OFF_SW4 + 131072 * 2;
constexpr size_t OFF_SORT   = ((OFF_WPT + 60 * 512 * 4) + 255) & ~(size_t)255; // kB*kN float4

DI int cellof(float x) {
  int c = (int)(x * (float)GRD);
  return min(GRD - 1, max(0, c));
}
DI unsigned orderable(float f) {
  unsigned u = __float_as_uint(f);
  return (u & 0x80000000u) ? ~u : (u | 0x80000000u);
}

// =====================  zero the sync/count region  =====================
__global__ void k_zero(uint32_t* p, int nwords) {
  int i = blockIdx.x * blockDim.x + threadIdx.x;
  int st = gridDim.x * blockDim.x;
  for (; i < nwords; i += st) p[i] = 0u;
}

// =====================  weight prep: B-fragment swizzle (f16) + WpT  =====================
DI void swz(const float* __restrict__ W, _Float16* __restrict__ sw,
            int total, int nks, int Kreal, int N, int i0, int st) {
  for (int i = i0; i < total; i += st) {
    int j = i & 7, lane = (i >> 3) & 63, rest = i >> 9;
    int ks = rest % nks, nt = rest / nks;
    int k = ks * 32 + ((lane >> 4) << 3) + j;
    int n = nt * 16 + (lane & 15);
    sw[i] = (_Float16)((k < Kreal) ? W[k * N + n] : 0.f);
  }
}

__global__ void k_prep(const float* __restrict__ W1, const float* __restrict__ W2,
                       const float* __restrict__ W3, const float* __restrict__ W4,
                       const float* __restrict__ Wp,
                       _Float16* __restrict__ sw1, _Float16* __restrict__ sw2,
                       _Float16* __restrict__ sw3, _Float16* __restrict__ sw4,
                       float* __restrict__ wpt) {
  int i0 = blockIdx.x * blockDim.x + threadIdx.x;
  int st = gridDim.x * blockDim.x;
  swz(W1, sw1, 2048, 1, 6, 64, i0, st);
  swz(W2, sw2, 8192, 2, 64, 128, i0, st);
  swz(W3, sw3, 32768, 4, 128, 256, i0, st);
  swz(W4, sw4, 131072, 8, 256, 512, i0, st);
  for (int i = i0; i < 60 * 512; i += st) { int n = i >> 9, k = i & 511; wpt[i] = Wp[k * 60 + n]; }
}

// =====================  device-wide phase barrier (co-resident workers)  =====================
DI void gbar(uint32_t* ctr, unsigned target) {
  __syncthreads();
  if (threadIdx.x == 0) {
    __hip_atomic_fetch_add(ctr, 1u, __ATOMIC_ACQ_REL, __HIP_MEMORY_SCOPE_AGENT);
    long bail = 0;
    while (__hip_atomic_load(ctr, __ATOMIC_ACQUIRE, __HIP_MEMORY_SCOPE_AGENT) < target) {
      __builtin_amdgcn_s_sleep(32);
      if (++bail > 100000000L) break;
    }
  }
  __syncthreads();
}

// =====================  FPS block (part of fused kernel)  =====================
DI void fps_block(const float* __restrict__ xyz, float* __restrict__ outC,
                  u64* __restrict__ fkey, int bi) {
  const int b = bi / FPS_SUB, sub = bi % FPS_SUB;
  const int tid = threadIdx.x;
  const int wave = tid >> 6, lane = tid & 63;
  const float* X = xyz + (size_t)b * kN * 3;
  float px[FPS_PT_T], py[FPS_PT_T], pz[FPS_PT_T], dd[FPS_PT_T];
#pragma unroll
  for (int j = 0; j < FPS_PT_T; ++j) {
    int p = sub * (kN / FPS_SUB) + j * FPS_TPB + tid;
    px[j] = X[3 * p]; py[j] = X[3 * p + 1]; pz[j] = X[3 * p + 2];
    dd[j] = 1e10f;
  }
  float lx = X[0], ly = X[1], lz = X[2];
  if (sub == 0 && tid == 0) {
    outC[(size_t)b * kG * 3 + 0] = lx;
    outC[(size_t)b * kG * 3 + 1] = ly;
    outC[(size_t)b * kG * 3 + 2] = lz;
  }
  __shared__ u64 s_key[4];
  __shared__ float s_x[4], s_y[4], s_z[4];
  __shared__ float4 sp;
  u64* keyB = fkey + (size_t)b * kG * (FPS_SUB * 4);

  for (int it = 1; it < kG; ++it) {
    float bnd = -1.0f, bx = 0.f, by = 0.f, bz = 0.f;
    int bp = 0;
#pragma unroll
    for (int j = 0; j < FPS_PT_T; ++j) {
      float dx = __fsub_rn(px[j], lx);
      float dy = __fsub_rn(py[j], ly);
      float dz = __fsub_rn(pz[j], lz);
      float d = __fadd_rn(__fadd_rn(__fmul_rn(dx, dx), __fmul_rn(dy, dy)), __fmul_rn(dz, dz));
      float nd = fminf(dd[j], d);
      dd[j] = nd;
      int p = sub * (kN / FPS_SUB) + j * FPS_TPB + tid;
      if (nd > bnd) { bnd = nd; bx = px[j]; by = py[j]; bz = pz[j]; bp = p; }
    }
    u64 best = ((u64)__float_as_uint(bnd) << 32) | (unsigned)(0xFFFFFFFFu - (unsigned)bp);
#pragma unroll
    for (int off = 32; off; off >>= 1) {
      u64 ok = __shfl_down(best, (unsigned)off);
      float ox = __shfl_down(bx, (unsigned)off);
      float oy = __shfl_down(by, (unsigned)off);
      float oz = __shfl_down(bz, (unsigned)off);
      if (ok > best) { best = ok; bx = ox; by = oy; bz = oz; }
    }
    if (lane == 0) { s_key[wave] = best; s_x[wave] = bx; s_y[wave] = by; s_z[wave] = bz; }
    __syncthreads();
    if (wave == 0) {
      int i4 = lane & 3;
      u64 kk = s_key[i4]; float kx = s_x[i4], ky = s_y[i4], kz = s_z[i4];
#pragma unroll
      for (int off = 2; off; off >>= 1) {
        u64 ok = __shfl_down(kk, (unsigned)off);
        float ox = __shfl_down(kx, (unsigned)off);
        float oy = __shfl_down(ky, (unsigned)off);
        float oz = __shfl_down(kz, (unsigned)off);
        if (ok > kk) { kk = ok; kx = ox; ky = oy; kz = oz; }
      }
      u64* slots = keyB + (size_t)it * (FPS_SUB * 4);
      if (lane == 0) {
        u64 tag = (unsigned)it;
        u64* my = slots + sub * 4;
        __hip_atomic_store(my + 1, ((u64)__float_as_uint(kx) << 32) | tag,
                           __ATOMIC_RELAXED, __HIP_MEMORY_SCOPE_AGENT);
        __hip_atomic_store(my + 2, ((u64)__float_as_uint(ky) << 32) | tag,
                           __ATOMIC_RELAXED, __HIP_MEMORY_SCOPE_AGENT);
        __hip_atomic_store(my + 3, ((u64)__float_as_uint(kz) << 32) | tag,
                           __ATOMIC_RELAXED, __HIP_MEMORY_SCOPE_AGENT);
        __hip_atomic_store(my + 0, kk, __ATOMIC_RELAXED, __HIP_MEMORY_SCOPE_AGENT);
      }
      u64 v = 0; bool okp; long bail = 0;
      do {
        if (lane < FPS_SUB * 4)
          v = __hip_atomic_load(slots + lane, __ATOMIC_RELAXED, __HIP_MEMORY_SCOPE_AGENT);
        okp = (lane >= FPS_SUB * 4) ||
              ((lane & 3) ? ((unsigned)v == (unsigned)it) : (v != 0ull));
      } while (!__all(okp) && ++bail < 200000000L);
      u64 key = (lane < FPS_SUB * 4 && (lane & 3) == 0) ? v : 0ull;
      int slot = lane >> 2;
#pragma unroll
      for (int off = 16; off >= 4; off >>= 1) {
        u64 ok = __shfl_down(key, (unsigned)off);
        int os = __shfl_down(slot, (unsigned)off);
        if (ok > key) { key = ok; slot = os; }
      }
      slot = __shfl(slot, 0);
      u64 vx = __shfl(v, slot * 4 + 1);
      u64 vy = __shfl(v, slot * 4 + 2);
      u64 vz = __shfl(v, slot * 4 + 3);
      if (lane == 0) {
        float wxc = __uint_as_float((unsigned)(vx >> 32));
        float wyc = __uint_as_float((unsigned)(vy >> 32));
        float wzc = __uint_as_float((unsigned)(vz >> 32));
        sp = make_float4(wxc, wyc, wzc, 0.f);
        if (sub == 0) {
          outC[((size_t)b * kG + it) * 3 + 0] = wxc;
          outC[((size_t)b * kG + it) * 3 + 1] = wyc;
          outC[((size_t)b * kG + it) * 3 + 2] = wzc;
        }
      }
    }
    __syncthreads();
    lx = sp.x; ly = sp.y; lz = sp.z;
  }
}

// =====================  bitonic sort (shared, 256 threads)  =====================
DI void bitonic(u64* a, int n, int tid) {
  for (int k = 2; k <= n; k <<= 1)
    for (int j = k >> 1; j > 0; j >>= 1) {
      __syncthreads();
      for (int i = tid; i < n; i += 256) {
        int ix = i ^ j;
        if (ix > i) {
          u64 x = a[i], y = a[ix];
          bool up = ((i & k) == 0);
          if ((x > y) == up) { a[i] = y; a[ix] = x; }
        }
      }
    }
  __syncthreads();
}

// =====================  MLP layers (f16 MFMA)  =====================
template <int Kdim, int Ndim, int SIN, int SOUT>
DI void mfma_layer(const _Float16* __restrict__ Xin, _Float16* __restrict__ Xout,
                   const _Float16* __restrict__ Wsw, const float* __restrict__ bias,
                   int wave, int lane) {
  constexpr int NKS = Kdim / 32;
  constexpr int NTW = Ndim / 64;
  constexpr int CH = (NTW < 4) ? NTW : 4;
  const int quad = lane >> 4, l16 = lane & 15;
  for (int c0 = 0; c0 < NTW; c0 += CH) {
    f32x4 acc[CH][4];
#pragma unroll
    for (int nt = 0; nt < CH; ++nt) {
      float bv = bias[wave * (Ndim / 4) + (c0 + nt) * 16 + l16];
#pragma unroll
      for (int m = 0; m < 4; ++m) acc[nt][m] = {bv, bv, bv, bv};
    }
#pragma unroll
    for (int ks = 0; ks < NKS; ++ks) {
      f16x8 af[4];
#pragma unroll
      for (int m = 0; m < 4; ++m)
        af[m] = *(const f16x8*)(Xin + (m * 16 + l16) * SIN + ks * 32 + quad * 8);
#pragma unroll
      for (int nt = 0; nt < CH; ++nt) {
        int ntg = wave * NTW + c0 + nt;
        f16x8 bf = *(const f16x8*)(Wsw + ((size_t)(ntg * NKS + ks) * 64 + lane) * 8);
#pragma unroll
        for (int m = 0; m < 4; ++m)
          acc[nt][m] = __builtin_amdgcn_mfma_f32_16x16x32_f16(af[m], bf, acc[nt][m], 0, 0, 0);
      }
    }
#pragma unroll
    for (int nt = 0; nt < CH; ++nt) {
      int col = wave * (Ndim / 4) + (c0 + nt) * 16 + l16;
#pragma unroll
      for (int m = 0; m < 4; ++m)
#pragma unroll
        for (int r = 0; r < 4; ++r) {
          int row = m * 16 + quad * 4 + r;
          Xout[row * SOUT + col] = (_Float16)fmaxf(acc[nt][m][r], 0.f);
        }
    }
  }
}

DI void mfma_layer4(const _Float16* __restrict__ Xin, const _Float16* __restrict__ Wsw,
                    const float* __restrict__ bias, float* __restrict__ maxv,
                    int wave, int lane) {
  constexpr int SIN = 264, NKS = 8, NTW = 8, CH = 4;
  const int quad = lane >> 4, l16 = lane & 15;
  for (int c0 = 0; c0 < NTW; c0 += CH) {
    f32x4 acc[CH][4];
#pragma unroll
    for (int nt = 0; nt < CH; ++nt) {
      float bv = bias[wave * 128 + (c0 + nt) * 16 + l16];
#pragma unroll
      for (int m = 0; m < 4; ++m) acc[nt][m] = {bv, bv, bv, bv};
    }
#pragma unroll
    for (int ks = 0; ks < NKS; ++ks) {
      f16x8 af[4];
#pragma unroll
      for (int m = 0; m < 4; ++m)
        af[m] = *(const f16x8*)(Xin + (m * 16 + l16) * SIN + ks * 32 + quad * 8);
#pragma unroll
      for (int nt = 0; nt < CH; ++nt) {
        int ntg = wave * NTW + c0 + nt;
        f16x8 bf = *(const f16x8*)(Wsw + ((size_t)(ntg * NKS + ks) * 64 + lane) * 8);
#pragma unroll
        for (int m = 0; m < 4; ++m)
          acc[nt][m] = __builtin_amdgcn_mfma_f32_16x16x32_f16(af[m], bf, acc[nt][m], 0, 0, 0);
      }
    }
#pragma unroll
    for (int nt = 0; nt < CH; ++nt) {
      float mx = 0.f;  // relu folded into max
#pragma unroll
      for (int m = 0; m < 4; ++m)
#pragma unroll
        for (int r = 0; r < 4; ++r) mx = fmaxf(mx, acc[nt][m][r]);
      mx = fmaxf(mx, __shfl_xor(mx, 16, 64));
      mx = fmaxf(mx, __shfl_xor(mx, 32, 64));
      if (quad == 0) maxv[wave * 128 + (c0 + nt) * 16 + l16] = mx;
    }
  }
}

// =====================  fused kernel  =====================
__global__ __launch_bounds__(256, 2) void k_fused(
    const float* __restrict__ xyz, const float* __restrict__ color,
    float* __restrict__ outC, float* __restrict__ outE,
    u64* __restrict__ fkey, uint32_t* __restrict__ ccnt,
    uint32_t* __restrict__ cstart, uint32_t* __restrict__ cur,
    float4* __restrict__ sorted, uint32_t* __restrict__ gs,
    const _Float16* __restrict__ sw1, const _Float16* __restrict__ sw2,
    const _Float16* __restrict__ sw3, const _Float16* __restrict__ sw4,
    const float* __restrict__ wpt,
    const float* __restrict__ b1, const float* __restrict__ b2,
    const float* __restrict__ b3, const float* __restrict__ b4,
    const float* __restrict__ bp) {
  const int bi = blockIdx.x;
  if (bi < NFPS) { fps_block(xyz, outC, fkey, bi); return; }

  // ---------------- worker block ----------------
  const int wj = bi - NFPS;           // 0..NWORK-1
  const int tid = threadIdx.x;
  const int wave = tid >> 6, lane = tid & 63;
  __shared__ __align__(16) char smem[65536];   // cand (64KB) ∪ {bufA,bufB,maxv,psum}
  __shared__ int nC;
  __shared__ float4 spc;
  __shared__ uint32_t s_part[256];
  u64* cand = (u64*)smem;

  // ---- grid build (overlapped with early FPS rounds) ----
  for (int i = wj * 256 + tid; i < kB * kN; i += NWORK * 256) {
    int b = i >> 16, p = i & (kN - 1);
    const float* q = xyz + ((size_t)b * kN + p) * 3;
    int cid = (cellof(q[2]) * GRD + cellof(q[1])) * GRD + cellof(q[0]);
    atomicAdd(&ccnt[b * NCELL + cid], 1u);
  }
  gbar(gs + 0, NWORK);
  if (wj < kB) {
    int b = wj;
    const uint32_t* cc = ccnt + (size_t)b * NCELL;
    uint32_t* cs = cstart + (size_t)b * (NCELL + 1);
    uint32_t* cu = cur + (size_t)b * NCELL;
    const int chunk = 32;
    int c0 = tid * chunk;
    uint32_t s = 0;
    for (int i = 0; i < chunk; ++i) { int c = c0 + i; if (c < NCELL) s += cc[c]; }
    s_part[tid] = s;
    __syncthreads();
    for (int off = 1; off < 256; off <<= 1) {
      uint32_t add = (tid >= off) ? s_part[tid - off] : 0u;
      __syncthreads();
      s_part[tid] += add;
      __syncthreads();
    }
    uint32_t run = s_part[tid] - s;
    for (int i = 0; i < chunk; ++i) {
      int c = c0 + i;
      if (c < NCELL) { cs[c] = run; cu[c] = run; run += cc[c]; }
    }
    if (tid == 255) cs[NCELL] = run;
  }
  gbar(gs + 1, NWORK);
  for (int i = wj * 256 + tid; i < kB * kN; i += NWORK * 256) {
    int b = i >> 16, p = i & (kN - 1);
    const float* q = xyz + ((size_t)b * kN + p) * 3;
    float x = q[0], y = q[1], z = q[2];
    int cid = (cellof(z) * GRD + cellof(y)) * GRD + cellof(x);
    uint32_t pos = atomicAdd(&cur[b * NCELL + cid], 1u);
    sorted[(size_t)b * kN + pos] = make_float4(x, y, z, __uint_as_float((unsigned)p));
  }
  gbar(gs + 2, NWORK);

  // ---- consume groups in production order: job j = it*4 + b ----
  for (int j = wj; j < kB * kG; j += NWORK) {
    const int it = j >> 2, b = j & 3;
    const float* X = xyz + (size_t)b * kN * 3;
    if (it == 0) {
      if (tid == 0) spc = make_float4(X[0], X[1], X[2], 0.f);
    } else if (tid < 64) {
      const u64* slots = fkey + ((size_t)b * kG + it) * (FPS_SUB * 4);
      const int pl = tid;
      u64 v = 0; bool okp; long bail = 0;
      for (;;) {
        if (pl < FPS_SUB * 4)
          v = __hip_atomic_load(slots + pl, __ATOMIC_RELAXED, __HIP_MEMORY_SCOPE_AGENT);
        okp = (pl >= FPS_SUB * 4) ||
              ((pl & 3) ? ((unsigned)v == (unsigned)it) : (v != 0ull));
        if (__all(okp)) break;
        __builtin_amdgcn_s_sleep(127);
        if (++bail > 50000000L) break;
      }
      u64 key = (pl < FPS_SUB * 4 && (pl & 3) == 0) ? v : 0ull;
      int slot = pl >> 2;
#pragma unroll
      for (int off = 16; off >= 4; off >>= 1) {
        u64 ok = __shfl_down(key, (unsigned)off);
        int os = __shfl_down(slot, (unsigned)off);
        if (ok > key) { key = ok; slot = os; }
      }
      slot = __shfl(slot, 0);
      u64 vx = __shfl(v, slot * 4 + 1);
      u64 vy = __shfl(v, slot * 4 + 2);
      u64 vz = __shfl(v, slot * 4 + 3);
      if (pl == 0)
        spc = make_float4(__uint_as_float((unsigned)(vx >> 32)),
                          __uint_as_float((unsigned)(vy >> 32)),
                          __uint_as_float((unsigned)(vz >> 32)), 0.f);
    }
    __syncthreads();
    const float cx = spc.x, cy = spc.y, cz = spc.z;

    // ---- KNN (expanding box + exact re-rank + bitonic) ----
    const float nc = __fadd_rn(__fadd_rn(__fmul_rn(cx, cx), __fmul_rn(cy, cy)), __fmul_rn(cz, cz));
    const float4* SP = sorted + (size_t)b * kN;
    const uint32_t* CS = cstart + (size_t)b * (NCELL + 1);
    const int ccx = cellof(cx), ccy = cellof(cy), ccz = cellof(cz);
    if (tid == 0) nC = 0;
    __syncthreads();
    int plox = 1, phix = 0, ploy = 1, phiy = 0, ploz = 1, phiz = 0;
    for (int r = 1; r <= GRD; ++r) {
      int lox = max(0, ccx - r), hix = min(GRD - 1, ccx + r);
      int loy = max(0, ccy - r), hiy = min(GRD - 1, ccy + r);
      int loz = max(0, ccz - r), hiz = min(GRD - 1, ccz + r);
      for (int z = loz; z <= hiz; ++z)
        for (int y = loy; y <= hiy; ++y) {
          bool rowPrev = (r > 1) && (z >= ploz && z <= phiz && y >= ploy && y <= phiy);
          for (int s = 0; s < 2; ++s) {
            int xa, xb;
            if (!rowPrev) { if (s) break; xa = lox; xb = hix; }
            else if (s == 0) { xa = lox; xb = plox - 1; }
            else { xa = phix + 1; xb = hix; }
            if (xa > xb) continue;
            int c0 = (z * GRD + y) * GRD + xa;
            int i0 = CS[c0];
            int i1 = CS[(z * GRD + y) * GRD + xb + 1];
            for (int i = i0 + tid; i < i1; i += 256) {
              float4 pt = SP[i];
              float npn = __fadd_rn(__fadd_rn(__fmul_rn(pt.x, pt.x), __fmul_rn(pt.y, pt.y)),
                                    __fmul_rn(pt.z, pt.z));
              float dot = __fadd_rn(__fadd_rn(__fmul_rn(cx, pt.x), __fmul_rn(cy, pt.y)),
                                    __fmul_rn(cz, pt.z));
              float sq = __fsub_rn(__fadd_rn(nc, npn), __fmul_rn(2.0f, dot));
              unsigned key = orderable(sq);
              int pos = atomicAdd(&nC, 1);
              if (pos < 8192)
                cand[pos] = ((u64)key << 32) | (unsigned)__float_as_uint(pt.w);
            }
          }
        }
      __syncthreads();
      int n = min(nC, 8192);
      float rc = 1e30f;
      if (lox > 0) rc = fminf(rc, cx - (float)lox * CW);
      if (hix < GRD - 1) rc = fminf(rc, (float)(hix + 1) * CW - cx);
      if (loy > 0) rc = fminf(rc, cy - (float)loy * CW);
      if (hiy < GRD - 1) rc = fminf(rc, (float)(hiy + 1) * CW - cy);
      if (loz > 0) rc = fminf(rc, cz - (float)loz * CW);
      if (hiz < GRD - 1) rc = fminf(rc, (float)(hiz + 1) * CW - cz);
      float r2 = (rc >= 1e29f) ? 3.0e38f : rc * rc * (1.0f - 1e-5f);
      unsigned keyR = orderable(r2);
      bool done = false;
      if (n >= kM) {
        int np2 = 1;
        while (np2 < n) np2 <<= 1;
        for (int i = n + tid; i < np2; i += 256) cand[i] = ~0ull;
        bitonic(cand, np2, tid);
        unsigned k63 = (unsigned)(cand[kM - 1] >> 32);
        done = (k63 <= keyR);
        if (tid == 0) nC = n;
      }
      __syncthreads();
      if (done) break;
      plox = lox; phix = hix; ploy = loy; phiy = hiy; ploz = loz; phiz = hiz;
    }

    // ---- MLP (reuses smem; neighbor indices straight from cand) ----
    uint32_t pidx = 0;
    if (tid < kM) pidx = (uint32_t)(cand[tid] & 0xFFFFFFFFu);
    __syncthreads();
    _Float16* bufA = (_Float16*)smem;
    _Float16* bufB = (_Float16*)(smem + 17408);
    float* maxv = (float*)smem;
    float* psum = (float*)(smem + 2048);
    if (tid < kM) {
      const float* xp = xyz + ((size_t)b * kN + pidx) * 3;
      const float* cp = color + ((size_t)b * kN + pidx) * 3;
      f16x8 v = {};
      v[0] = (_Float16)__fsub_rn(xp[0], cx);
      v[1] = (_Float16)__fsub_rn(xp[1], cy);
      v[2] = (_Float16)__fsub_rn(xp[2], cz);
      v[3] = (_Float16)cp[0];
      v[4] = (_Float16)cp[1];
      v[5] = (_Float16)cp[2];
      f16x8 zf = {};
      *(f16x8*)(bufA + tid * 40 + 0) = v;
      *(f16x8*)(bufA + tid * 40 + 8) = zf;
      *(f16x8*)(bufA + tid * 40 + 16) = zf;
      *(f16x8*)(bufA + tid * 40 + 24) = zf;
    }
    __syncthreads();
    mfma_layer<32, 64, 40, 72>(bufA, bufB, sw1, b1, wave, lane);
    __syncthreads();
    mfma_layer<64, 128, 72, 136>(bufB, bufA, sw2, b2, wave, lane);
    __syncthreads();
    mfma_layer<128, 256, 136, 264>(bufA, bufB, sw3, b3, wave, lane);
    __syncthreads();
    mfma_layer4(bufB, sw4, b4, maxv, wave, lane);
    __syncthreads();
    if (tid < 240) {
      int jj = tid >> 2, q = tid & 3;
      const float* w = wpt + (size_t)jj * 512 + q * 128;
      float s = 0.f;
#pragma unroll 4
      for (int k = 0; k < 128; ++k) s = fmaf(maxv[q * 128 + k], w[k], s);
      psum[tid] = s;
    }
    __syncthreads();
    if (tid < kE) {
      float e = __fadd_rn(__fadd_rn(psum[tid * 4 + 0], psum[tid * 4 + 1]),
                          __fadd_rn(psum[tid * 4 + 2], psum[tid * 4 + 3])) + bp[tid];
      outE[((size_t)b * kG + it) * kE + tid] = e;
    }
    __syncthreads();  // smem reuse fence before next job
  }
}

// =====================  launch  =====================
extern "C" void kernel_launch(void* const* d_in, const int* in_sizes, int n_in,
                              void* d_out, int out_size, void* d_ws, size_t ws_size,
                              hipStream_t stream) {
  (void)in_sizes; (void)n_in; (void)out_size; (void)ws_size;
  const float* xyz = (const float*)d_in[0];
  const float* color = (const float*)d_in[1];
  const float* W1 = (const float*)d_in[2];
  const float* b1 = (const float*)d_in[3];
  const float* W2 = (const float*)d_in[4];
  const float* b2 = (const float*)d_in[5];
  const float* W3 = (const float*)d_in[6];
  const float* b3 = (const float*)d_in[7];
  const float* W4 = (const float*)d_in[8];
  const float* b4 = (const float*)d_in[9];
  const float* Wp = (const float*)d_in[10];
  const float* bp = (const float*)d_in[11];

  char* ws = (char*)d_ws;
  auto fkey = (u64*)(ws + OFF_FKEY);
  auto ccnt = (uint32_t*)(ws + OFF_CCNT);
  auto gs = (uint32_t*)(ws + OFF_GS);
  auto cstart = (uint32_t*)(ws + OFF_CSTART);
  auto cur = (uint32_t*)(ws + OFF_CUR);
  auto sw1 = (_Float16*)(ws + OFF_SW1);
  auto sw2 = (_Float16*)(ws + OFF_SW2);
  auto sw3 = (_Float16*)(ws + OFF_SW3);
  auto sw4 = (_Float16*)(ws + OFF_SW4);
  auto wpt = (float*)(ws + OFF_WPT);
  auto sorted = (float4*)(ws + OFF_SORT);

  float* outE = (float*)d_out;
  float* outC = outE + (size_t)kB * kG * kE;

  k_zero<<<128, 256, 0, stream>>>((uint32_t*)ws, (int)(ZERO_BYTES / 4));
  k_prep<<<256, 256, 0, stream>>>(W1, W2, W3, W4, Wp, sw1, sw2, sw3, sw4, wpt);
  k_fused<<<NBLK, 256, 0, stream>>>(xyz, color, outC, outE, fkey, ccnt, cstart, cur,
                                    sorted, gs, sw1, sw2, sw3, sw4, wpt,
                                    b1, b2, b3, b4, bp);
}